// Round 10
// baseline (173.384 us; speedup 1.0000x reference)
//
#include <hip/hip_runtime.h>

namespace {

constexpr int Cn   = 256;
constexpr int Hh   = 128;
constexpr int Ww   = 128;
constexpr int HW   = Hh * Ww;
constexpr int TW   = 16;              // tile width
constexpr int TH   = 8;               // tile height
constexpr int CCH  = 16;              // channels per LDS chunk (r10: 8->16,
                                      //  halves barrier-convoy count)
constexpr int NCH  = Cn / CCH;        // 16 chunks
constexpr int HALO = 4;
constexpr int SRR  = 10;              // staged rows per type: h+w, h<8, w<3
constexpr int SC4  = 6;               // float4 per staged row (24 cols)
constexpr int SS   = 28;              // padded row stride (floats), 7 granules (odd)
constexpr int SCH  = SRR * SS;        // 280 floats per channel
constexpr int NOFF = 81;
constexpr int NF4  = CCH * SRR * SC4; // 960 staged float4 per chunk = 5*192 exactly
constexpr int SLT  = NF4 / 192;       // 5 staging slots per thread

// 192 threads = 3 waves. Block type T covers di in {3T,3T+1,3T+2}; wave w <->
// di = 3T+w (o = 9*di+dj, each o written once). Lane l: h=l&7, m=(l>>3)&1
// (px cols 8m..8m+7), c4=l>>4 (4-way channel split, shuffle-reduced).
// r9 lesson (counters): no pipe saturated (VALU 22%, DS 40%, HBM 22%) --
// the per-chunk barrier's vmcnt(0) drain exposes ~2-3K cyc loaded-latency
// per phase. Fewer, fatter phases amortize it.

__global__ __launch_bounds__(192, 3)
void costvol_kernel(const float* __restrict__ x1,
                    const float* __restrict__ x2,
                    float* __restrict__ out)
{
  __shared__ float s2[2][CCH * SCH];   // 35,840 B

  const int t  = threadIdx.x;
  const int wv = t >> 6;               // 0..2
  const int l  = t & 63;
  const int h  = l & 7;
  const int m  = (l >> 3) & 1;
  const int c4 = l >> 4;

  const int tx = blockIdx.x;
  const int yy = blockIdx.y;           // type + 3*ty (same-tile types adjacent
  const int ty = yy / 3;               //  in linear id -> same XCD/L2)
  const int tp = yy - 3 * ty;          // block type 0..2
  const int b  = blockIdx.z;
  const int x0 = tx * TW;
  const int y0 = ty * TH;

  const float* g1 = x1 + (size_t)b * Cn * HW + (size_t)(y0 + h) * Ww + (x0 + 8 * m);
  const float* g2 = x2 + (size_t)b * Cn * HW;

  // ---- float4-granular staging: slot j stages float4 f = t + 192*j ----
  int  soff[SLT], swr[SLT];
  bool sval[SLT];
#pragma unroll
  for (int j = 0; j < SLT; ++j) {
    const int f    = t + 192 * j;      // < 960 always (5*192 exact)
    const int ch   = f / (SRR * SC4);
    const int rem  = f % (SRR * SC4);
    const int row  = rem / SC4, col4 = rem % SC4;
    const int gy = y0 - HALO + 3 * tp + row;
    const int gx = x0 - HALO + 4 * col4;          // 16B-aligned granule
    const bool ok = ((unsigned)gy < (unsigned)Hh) && ((unsigned)gx < (unsigned)Ww);
    sval[j] = ok;
    soff[j] = ok ? (ch * HW + gy * Ww + gx) : 0;
    swr[j]  = ch * SCH + row * SS + 4 * col4;
  }

  float4 rs[SLT];
  auto stage_load = [&](int k) {
    const size_t cb = (size_t)(k * CCH) * HW;
#pragma unroll
    for (int j = 0; j < SLT; ++j)
      rs[j] = sval[j] ? *reinterpret_cast<const float4*>(g2 + cb + soff[j])
                      : float4{0.f, 0.f, 0.f, 0.f};
  };
  auto stage_write = [&](int nb) {
    float* s = s2[nb];
#pragma unroll
    for (int j = 0; j < SLT; ++j)
      *reinterpret_cast<float4*>(s + swr[j]) = rs[j];
  };

  float acc[9][8];
#pragma unroll
  for (int d = 0; d < 9; ++d)
#pragma unroll
    for (int p = 0; p < 8; ++p) acc[d][p] = 0.0f;

  const int rbase = (h + wv) * SS + 8 * m;   // stage-relative window row

  stage_load(0);
  stage_write(0);
  __syncthreads();

  for (int k = 0; k < NCH; ++k) {
    if (k + 1 < NCH) stage_load(k + 1);        // issue early: in flight for the
                                               // whole 576-cyc compute phase
    const float* sc_ = s2[k & 1];
#pragma unroll
    for (int s = 0; s < 4; ++s) {              // 4 channel-steps, barrier-free
      const size_t c = (size_t)(CCH * k + 4 * s + c4) * HW;
      const float4 a0 = *reinterpret_cast<const float4*>(g1 + c);
      const float4 a1 = *reinterpret_cast<const float4*>(g1 + c + 4);
      const float* bp = sc_ + (4 * s + c4) * SCH + rbase;
      float w[16];
      *reinterpret_cast<float4*>(w)      = *reinterpret_cast<const float4*>(bp);
      *reinterpret_cast<float4*>(w + 4)  = *reinterpret_cast<const float4*>(bp + 4);
      *reinterpret_cast<float4*>(w + 8)  = *reinterpret_cast<const float4*>(bp + 8);
      *reinterpret_cast<float4*>(w + 12) = *reinterpret_cast<const float4*>(bp + 12);
      const float av[8] = {a0.x, a0.y, a0.z, a0.w, a1.x, a1.y, a1.z, a1.w};
#pragma unroll
      for (int dj = 0; dj < 9; ++dj)
#pragma unroll
        for (int p = 0; p < 8; ++p)
          acc[dj][p] = fmaf(av[p], w[p + dj], acc[dj][p]);
    }
    if (k + 1 < NCH) stage_write((k + 1) & 1); // write late (T14)
    __syncthreads();
  }

  // ---- epilogue: reduce 4-way channel split (lanes l, l+16, l+32, l+48) ----
#pragma unroll
  for (int dj = 0; dj < 9; ++dj)
#pragma unroll
    for (int p = 0; p < 8; ++p) {
      float v = acc[dj][p];
      v += __shfl_down(v, 32);
      v += __shfl_down(v, 16);
      acc[dj][p] = v;
    }

  if (l < 16) {
    const float invc = 1.0f / (float)Cn;
    const int y  = y0 + h;
    const int xb = x0 + 8 * m;
    const int di = 3 * tp + wv;
#pragma unroll
    for (int dj = 0; dj < 9; ++dj) {
      const int o = di * 9 + dj;
      float* op = out + (((size_t)b * NOFF + o) * Hh + y) * Ww + xb;
      float4 v0, v1;
      v0.x = acc[dj][0] * invc; v0.y = acc[dj][1] * invc;
      v0.z = acc[dj][2] * invc; v0.w = acc[dj][3] * invc;
      v1.x = acc[dj][4] * invc; v1.y = acc[dj][5] * invc;
      v1.z = acc[dj][6] * invc; v1.w = acc[dj][7] * invc;
      *reinterpret_cast<float4*>(op)     = v0;
      *reinterpret_cast<float4*>(op + 4) = v1;
    }
  }
}

} // namespace

extern "C" void kernel_launch(void* const* d_in, const int* in_sizes, int n_in,
                              void* d_out, int out_size, void* d_ws, size_t ws_size,
                              hipStream_t stream) {
  const float* x1 = (const float*)d_in[0];
  const float* x2 = (const float*)d_in[1];
  float* out = (float*)d_out;

  // y encodes (type + 3*ty): sibling types of one tile are adjacent in
  // linear id -> same XCD -> shared x1/x2 tile data stays in that L2.
  dim3 grid(Ww / TW, 3 * (Hh / TH), 4);   // 8 x 48 x 4 = 1536 blocks
  dim3 block(192);                        // 3 waves: wave w <-> di = 3*type+w
  costvol_kernel<<<grid, block, 0, stream>>>(x1, x2, out);
}

// Round 11
// 80.189 us; speedup vs baseline: 2.1622x; 2.1622x over previous
//
#include <hip/hip_runtime.h>

namespace {

constexpr int Cn   = 256;            // channels
constexpr int Hh   = 128;
constexpr int Ww   = 128;
constexpr int HW   = Hh * Ww;
constexpr int TILE = 16;             // spatial tile edge
constexpr int CCH  = 8;              // channels per LDS chunk
constexpr int NCH  = Cn / CCH;       // 32 chunks
constexpr int HALO = 4;
constexpr int X2T  = 24;             // x2 tile rows/cols staged
constexpr int X2S  = 48;             // padded row stride (floats) = 12 granules:
                                     //  8-lane phase {h=2q,2q+1; m=0..3} hits
                                     //  granules {m, m+4} mod 8 -> conflict-free
constexpr int X2CH = X2T * X2S;      // 1152 floats per channel (288 granules %8==0)
constexpr int NOFF = 81;

// 576 threads = 9 waves; wave wv <-> window row di = wv (o = 9*wv + dj).
// Lane l: h = l>>2 (tile row, keeps x1/out coalesced), m = l&3 (cols 4m..4m+3).
// r5 (77us bench) + ONE change: X2S 28->48 kills the 2-way read conflicts
// (8.26M cycles, ~13us/CU of its profile). Everything else identical.

__global__ __launch_bounds__(576, 1)
void costvol_kernel(const float* __restrict__ x1,
                    const float* __restrict__ x2,
                    float* __restrict__ out)
{
  __shared__ float s2[2][CCH * X2CH];   // 73,728 B (1 block/CU)

  const int t    = threadIdx.x;
  const int wv   = t >> 6;             // di = 0..8
  const int lane = t & 63;
  const int h    = lane >> 2;          // tile row 0..15
  const int m    = lane & 3;           // pixel group: cols 4m..4m+3

  const int tx = blockIdx.x, ty = blockIdx.y, b = blockIdx.z;
  const int x0 = tx * TILE, y0 = ty * TILE;

  // x1: this lane's 4 pixels; same address across all 9 waves -> L1 broadcast
  const float* g1 = x1 + (size_t)b * Cn * HW + (size_t)(y0 + h) * Ww + (x0 + 4 * m);
  const float* g2 = x2 + (size_t)b * Cn * HW;

  // ---- x2 staging map: 8 groups of 72 threads; group stages one channel ----
  // thread (g=t/72, r=t%72) stages elements e = r + 72*j, j=0..7 of the 24x24
  // tile: row = r/24 + 3j, col = r%24 (col constant per thread).
  const int   g    = t / 72;
  const int   r    = t % 72;
  const int   rrow = r / 24;
  const int   rcol = r % 24;
  const float* gc  = g2 + (size_t)g * HW;

  const int  gx   = x0 - HALO + rcol;
  const bool gxok = ((unsigned)gx < (unsigned)Ww);
  int  off[8];
  bool val[8];
#pragma unroll
  for (int j = 0; j < 8; ++j) {
    const int gy = y0 - HALO + rrow + 3 * j;
    const bool ok = gxok && ((unsigned)gy < (unsigned)Hh);
    val[j] = ok;
    off[j] = ok ? (gy * Ww + gx) : 0;
  }
  const int lbase = g * X2CH + rrow * X2S + rcol;   // + j*3*X2S per element

  float rs[8];
  auto stage_load = [&](int k) {
    const size_t cb = (size_t)(k * CCH) * HW;
#pragma unroll
    for (int j = 0; j < 8; ++j)
      rs[j] = val[j] ? gc[cb + off[j]] : 0.0f;
  };
  auto stage_write = [&](int nb) {
    float* s = s2[nb];
#pragma unroll
    for (int j = 0; j < 8; ++j)
      s[lbase + j * 3 * X2S] = rs[j];
  };

  float acc[9][4];
#pragma unroll
  for (int d = 0; d < 9; ++d)
#pragma unroll
    for (int p = 0; p < 4; ++p) acc[d][p] = 0.0f;

  // LDS read base for this lane's window row: row (h+wv), cols 4m..4m+11
  const int rbase = (h + wv) * X2S + 4 * m;

  stage_load(0);
  stage_write(0);
  __syncthreads();

  for (int k = 0; k < NCH; ++k) {
    if (k + 1 < NCH) stage_load(k + 1);            // issue early (T14)
    const float* sc = s2[k & 1];
#pragma unroll
    for (int cc = 0; cc < CCH; ++cc) {
      const float4 a = *reinterpret_cast<const float4*>(
          g1 + (size_t)(k * CCH + cc) * HW);
      const float* bp = sc + cc * X2CH + rbase;
      float w[12];
      *reinterpret_cast<float4*>(w)     = *reinterpret_cast<const float4*>(bp);
      *reinterpret_cast<float4*>(w + 4) = *reinterpret_cast<const float4*>(bp + 4);
      *reinterpret_cast<float4*>(w + 8) = *reinterpret_cast<const float4*>(bp + 8);
#pragma unroll
      for (int dj = 0; dj < 9; ++dj) {
        acc[dj][0] = fmaf(a.x, w[dj + 0], acc[dj][0]);
        acc[dj][1] = fmaf(a.y, w[dj + 1], acc[dj][1]);
        acc[dj][2] = fmaf(a.z, w[dj + 2], acc[dj][2]);
        acc[dj][3] = fmaf(a.w, w[dj + 3], acc[dj][3]);
      }
    }
    if (k + 1 < NCH) stage_write((k + 1) & 1);     // write late
    __syncthreads();
  }

  // ---- epilogue: o = 9*di + dj; each (b,o,y,x) written exactly once ----
  const float invc = 1.0f / (float)Cn;
  const int y  = y0 + h;
  const int xb = x0 + 4 * m;
#pragma unroll
  for (int dj = 0; dj < 9; ++dj) {
    const int o = wv * 9 + dj;
    float4 v;
    v.x = acc[dj][0] * invc;
    v.y = acc[dj][1] * invc;
    v.z = acc[dj][2] * invc;
    v.w = acc[dj][3] * invc;
    *reinterpret_cast<float4*>(out + (((size_t)b * NOFF + o) * Hh + y) * Ww + xb) = v;
  }
}

} // namespace

extern "C" void kernel_launch(void* const* d_in, const int* in_sizes, int n_in,
                              void* d_out, int out_size, void* d_ws, size_t ws_size,
                              hipStream_t stream) {
  const float* x1 = (const float*)d_in[0];
  const float* x2 = (const float*)d_in[1];
  float* out = (float*)d_out;

  dim3 grid(Ww / TILE, Hh / TILE, 4);   // 8 x 8 x 4 = 256 blocks (1/CU)
  dim3 block(576);                      // 9 waves: wave wv <-> window row di
  costvol_kernel<<<grid, block, 0, stream>>>(x1, x2, out);
}

// Round 12
// 75.375 us; speedup vs baseline: 2.3003x; 1.0639x over previous
//
#include <hip/hip_runtime.h>

namespace {

constexpr int Cn   = 256;            // channels
constexpr int Hh   = 128;
constexpr int Ww   = 128;
constexpr int HW   = Hh * Ww;
constexpr int TILE = 16;             // spatial tile edge
constexpr int CCH  = 8;              // channels per LDS chunk
constexpr int NCH  = Cn / CCH;       // 32 chunks
constexpr int HALO = 4;
constexpr int X2T  = 24;             // x2 tile rows/cols staged
constexpr int X2S  = 48;             // padded row stride = 12 granules ->
                                     //  conflict-free b128 reads (r11-verified:
                                     //  8.26M -> 1.18M conflict cycles)
constexpr int X2CH = X2T * X2S;      // 1152 floats per channel
constexpr int NOFF = 81;

// 576 threads = 9 waves; wave wv <-> window row di = wv (o = 9*wv + dj).
// Lane l: h = l>>2 (tile row), m = l&3 (cols 4m..4m+3).
// r12 = r11 + ILP restructure: per half-chunk (4 ch) batch ALL loads
// (4 x1 float4 + 12 ds_read_b128) before the 144-FMA cluster, and move
// stage_write between the halves so rs-latency hides under half-1 compute
// and half-2 compute runs after the write (T14). r11's counters showed
// 7.9K cyc/phase vs ~2.6K max pipe demand -- pure serialized latency.

__global__ __launch_bounds__(576, 1)
void costvol_kernel(const float* __restrict__ x1,
                    const float* __restrict__ x2,
                    float* __restrict__ out)
{
  __shared__ float s2[2][CCH * X2CH];   // 73,728 B (1 block/CU)

  const int t    = threadIdx.x;
  const int wv   = t >> 6;             // di = 0..8
  const int lane = t & 63;
  const int h    = lane >> 2;          // tile row 0..15
  const int m    = lane & 3;           // pixel group: cols 4m..4m+3

  const int tx = blockIdx.x, ty = blockIdx.y, b = blockIdx.z;
  const int x0 = tx * TILE, y0 = ty * TILE;

  const float* g1 = x1 + (size_t)b * Cn * HW + (size_t)(y0 + h) * Ww + (x0 + 4 * m);
  const float* g2 = x2 + (size_t)b * Cn * HW;

  // ---- x2 staging map: 8 groups of 72 threads; group stages one channel ----
  const int   g    = t / 72;
  const int   r    = t % 72;
  const int   rrow = r / 24;
  const int   rcol = r % 24;
  const float* gc  = g2 + (size_t)g * HW;

  const int  gx   = x0 - HALO + rcol;
  const bool gxok = ((unsigned)gx < (unsigned)Ww);
  int  off[8];
  bool val[8];
#pragma unroll
  for (int j = 0; j < 8; ++j) {
    const int gy = y0 - HALO + rrow + 3 * j;
    const bool ok = gxok && ((unsigned)gy < (unsigned)Hh);
    val[j] = ok;
    off[j] = ok ? (gy * Ww + gx) : 0;
  }
  const int lbase = g * X2CH + rrow * X2S + rcol;

  float rs[8];
  auto stage_load = [&](int k) {
    const size_t cb = (size_t)(k * CCH) * HW;
#pragma unroll
    for (int j = 0; j < 8; ++j)
      rs[j] = val[j] ? gc[cb + off[j]] : 0.0f;
  };
  auto stage_write = [&](int nb) {
    float* s = s2[nb];
#pragma unroll
    for (int j = 0; j < 8; ++j)
      s[lbase + j * 3 * X2S] = rs[j];
  };

  float acc[9][4];
#pragma unroll
  for (int d = 0; d < 9; ++d)
#pragma unroll
    for (int p = 0; p < 4; ++p) acc[d][p] = 0.0f;

  const int rbase = (h + wv) * X2S + 4 * m;

  // ---- batched half-chunk: load 4 channels' operands, then 144 FMAs ----
  auto half = [&](int k, int hc, const float* sc) {
    float4 a[4];
    float  w[4][12];
#pragma unroll
    for (int cc = 0; cc < 4; ++cc) {
      a[cc] = *reinterpret_cast<const float4*>(
          g1 + (size_t)(k * CCH + 4 * hc + cc) * HW);
      const float* bp = sc + (4 * hc + cc) * X2CH + rbase;
      *reinterpret_cast<float4*>(w[cc])     = *reinterpret_cast<const float4*>(bp);
      *reinterpret_cast<float4*>(w[cc] + 4) = *reinterpret_cast<const float4*>(bp + 4);
      *reinterpret_cast<float4*>(w[cc] + 8) = *reinterpret_cast<const float4*>(bp + 8);
    }
#pragma unroll
    for (int cc = 0; cc < 4; ++cc)
#pragma unroll
      for (int dj = 0; dj < 9; ++dj) {
        acc[dj][0] = fmaf(a[cc].x, w[cc][dj + 0], acc[dj][0]);
        acc[dj][1] = fmaf(a[cc].y, w[cc][dj + 1], acc[dj][1]);
        acc[dj][2] = fmaf(a[cc].z, w[cc][dj + 2], acc[dj][2]);
        acc[dj][3] = fmaf(a[cc].w, w[cc][dj + 3], acc[dj][3]);
      }
  };

  stage_load(0);
  stage_write(0);
  __syncthreads();

  for (int k = 0; k < NCH; ++k) {
    if (k + 1 < NCH) stage_load(k + 1);            // issue early
    const float* sc = s2[k & 1];
    half(k, 0, sc);                                // covers rs latency
    if (k + 1 < NCH) stage_write((k + 1) & 1);     // write mid-phase (T14)
    half(k, 1, sc);                                // runs after the write
    __syncthreads();
  }

  // ---- epilogue: o = 9*di + dj; each (b,o,y,x) written exactly once ----
  const float invc = 1.0f / (float)Cn;
  const int y  = y0 + h;
  const int xb = x0 + 4 * m;
#pragma unroll
  for (int dj = 0; dj < 9; ++dj) {
    const int o = wv * 9 + dj;
    float4 v;
    v.x = acc[dj][0] * invc;
    v.y = acc[dj][1] * invc;
    v.z = acc[dj][2] * invc;
    v.w = acc[dj][3] * invc;
    *reinterpret_cast<float4*>(out + (((size_t)b * NOFF + o) * Hh + y) * Ww + xb) = v;
  }
}

} // namespace

extern "C" void kernel_launch(void* const* d_in, const int* in_sizes, int n_in,
                              void* d_out, int out_size, void* d_ws, size_t ws_size,
                              hipStream_t stream) {
  const float* x1 = (const float*)d_in[0];
  const float* x2 = (const float*)d_in[1];
  float* out = (float*)d_out;

  dim3 grid(Ww / TILE, Hh / TILE, 4);   // 8 x 8 x 4 = 256 blocks (1/CU)
  dim3 block(576);                      // 9 waves: wave wv <-> window row di
  costvol_kernel<<<grid, block, 0, stream>>>(x1, x2, out);
}